// Round 3
// baseline (821.500 us; speedup 1.0000x reference)
//
#include <hip/hip_runtime.h>

#define NL 8
#define NM 8192
#define ND 16
#define NH 256
#define NF 64
#define NN (NL * NM)

__device__ __forceinline__ float lrelu(float x) { return fmaxf(x, 0.1f * x); }

// ---------- precompute attention constants ----------
__global__ void precomp_kernel(const float* __restrict__ W_t2, const float* __restrict__ b_t2,
                               const float* __restrict__ W_p2, const float* __restrict__ b_p2,
                               const float* __restrict__ av, float* __restrict__ cst)
{
    int t = threadIdx.x;
    if (t < 32) {
        float w = 0.f;
        for (int q = 0; q < 32; ++q) w += W_t2[t * 32 + q] * av[q];
        cst[t] = w;
    } else {
        int j = t - 32;
        float w = 0.f;
        for (int k = 0; k < 32; ++k) w += W_p2[j * 32 + k] * av[32 + k];
        cst[32 + j] = w;
    }
    if (t == 0)  { float s = 0.f; for (int q = 0; q < 32; ++q) s += b_t2[q] * av[q];      cst[64] = s; }
    if (t == 33) { float s = 0.f; for (int k = 0; k < 32; ++k) s += b_p2[k] * av[32 + k]; cst[65] = s; }
}

// ---------- Level 0: h = mlp_pi(delay), 512 thr / 32 rows ----------
__global__ __launch_bounds__(512) void level0_kernel(
    const float* __restrict__ delay,
    const float* __restrict__ W1, const float* __restrict__ b1,
    const float* __restrict__ W2, const float* __restrict__ b2,
    float* __restrict__ h_all)
{
    const int tid = threadIdx.x;
    const int row0 = blockIdx.x * 32;
    __shared__ __align__(16) float sH[32][128];

    for (int x = tid; x < 32 * 128; x += 512) {
        int r = x >> 7, j = x & 127;
        sH[r][j] = lrelu(delay[row0 + r] * W1[j] + b1[j]);
    }
    __syncthreads();

    const int tj = tid & 63, tr = tid >> 6;
    float acc[4][4];
    #pragma unroll
    for (int a = 0; a < 4; ++a)
        #pragma unroll
        for (int b = 0; b < 4; ++b) acc[a][b] = 0.f;

    for (int k = 0; k < 128; k += 4) {
        float4 w0 = *(const float4*)(W2 + (size_t)(k + 0) * 256 + tj * 4);
        float4 w1 = *(const float4*)(W2 + (size_t)(k + 1) * 256 + tj * 4);
        float4 w2 = *(const float4*)(W2 + (size_t)(k + 2) * 256 + tj * 4);
        float4 w3 = *(const float4*)(W2 + (size_t)(k + 3) * 256 + tj * 4);
        #pragma unroll
        for (int rr = 0; rr < 4; ++rr) {
            float4 xv = *(const float4*)(&sH[tr * 4 + rr][k]);
            acc[rr][0] += xv.x * w0.x + xv.y * w1.x + xv.z * w2.x + xv.w * w3.x;
            acc[rr][1] += xv.x * w0.y + xv.y * w1.y + xv.z * w2.y + xv.w * w3.y;
            acc[rr][2] += xv.x * w0.z + xv.y * w1.z + xv.z * w2.z + xv.w * w3.z;
            acc[rr][3] += xv.x * w0.w + xv.y * w1.w + xv.z * w2.w + xv.w * w3.w;
        }
    }
    float4 bv = *(const float4*)(b2 + tj * 4);
    #pragma unroll
    for (int rr = 0; rr < 4; ++rr) {
        float4 o;
        o.x = acc[rr][0] + bv.x; o.y = acc[rr][1] + bv.y;
        o.z = acc[rr][2] + bv.z; o.w = acc[rr][3] + bv.w;
        *(float4*)(h_all + (size_t)(row0 + tr * 4 + rr) * NH + tj * 4) = o;
    }
}

// ---------- Fused per-level kernel: attention (reg-resident) + mlp_n ----------
// 512 threads = 8 waves; wave w computes attention for 4 rows -> sX; then block GEMM.
__global__ __launch_bounds__(512, 4) void level_kernel(
    const float* __restrict__ h_all, const float* __restrict__ feat,
    const float* __restrict__ bit_pos, const int* __restrict__ nbr_idx,
    const float* __restrict__ W_t1, const float* __restrict__ b_t1,
    const float* __restrict__ W_p1, const float* __restrict__ b_p1,
    const float* __restrict__ av, const float* __restrict__ cst,
    const float* __restrict__ W1, const float* __restrict__ b1,
    const float* __restrict__ W2, const float* __restrict__ b2,
    const int* __restrict__ is_po,
    float* __restrict__ h_out, int level)
{
    const int tid = threadIdx.x;
    const int w = tid >> 6, lane = tid & 63;
    const int row0 = blockIdx.x * 32;
    __shared__ __align__(16) float sX[32][NH];
    __shared__ __align__(16) float sH[32][128];

    const float4 av4 = *(const float4*)(av + 64 + lane * 4);

    // ---- Phase A: attention, 4 rows per wave, h_src in registers ----
    #pragma unroll 1
    for (int mi = 0; mi < 4; ++mi) {
        const int mrow = w * 4 + mi;
        const int m = row0 + mrow;

        int idx_l = 0;
        if (lane < ND) idx_l = nbr_idx[((size_t)(level - 1) * NM + m) * ND + lane];

        // coalesced gather: r[d] = h_src[d][lane*4 .. lane*4+3]
        float4 r[16];
        #pragma unroll
        for (int d = 0; d < 16; ++d) {
            int rowi = __shfl(idx_l, d);
            r[d] = *(const float4*)(h_all + (size_t)rowi * NH + lane * 4);
        }

        // e_h[d]: per-lane partial dot, then 64-lane butterfly (all lanes get totals)
        float eh[16];
        #pragma unroll
        for (int d = 0; d < 16; ++d)
            eh[d] = r[d].x * av4.x + r[d].y * av4.y + r[d].z * av4.z + r[d].w * av4.w;
        #pragma unroll
        for (int off = 1; off < 64; off <<= 1) {
            #pragma unroll
            for (int d = 0; d < 16; ++d) eh[d] += __shfl_xor(eh[d], off);
        }

        // e_p (collapsed mlp_p), lanes 0..15
        float ep = 0.f;
        if (lane < ND) {
            float x = bit_pos[((size_t)(level - 1) * NM + m) * ND + lane];
            #pragma unroll 8
            for (int j = 0; j < 32; ++j)
                ep += cst[32 + j] * lrelu(x * W_p1[j] + b_p1[j]);
            ep += cst[65];
        }

        // e_t (collapsed mlp_t), lanes 0..31
        float et = 0.f;
        if (lane < 32) {
            const float* frow = feat + (size_t)(level * NM + m) * NF;
            float acc = b_t1[lane];
            #pragma unroll 8
            for (int f = 0; f < NF; ++f) acc += frow[f] * W_t1[f * 32 + lane];
            et = lrelu(acc) * cst[lane];
        }
        #pragma unroll
        for (int off = 1; off < 32; off <<= 1) et += __shfl_xor(et, off);
        const float etb = __shfl(et, 0) + cst[64];

        // softmax over 16 (redundant per lane, zero shuffles)
        float e[16];
        float mx = -1e30f;
        #pragma unroll
        for (int d = 0; d < 16; ++d) {
            e[d] = eh[d] + __shfl(ep, d) + etb;
            mx = fmaxf(mx, e[d]);
        }
        float s = 0.f;
        #pragma unroll
        for (int d = 0; d < 16; ++d) { e[d] = __expf(e[d] - mx); s += e[d]; }
        const float inv = 1.f / s;

        // weighted sum entirely in registers
        float4 acc4 = make_float4(0.f, 0.f, 0.f, 0.f);
        #pragma unroll
        for (int d = 0; d < 16; ++d) {
            float a = e[d] * inv;
            acc4.x += a * r[d].x; acc4.y += a * r[d].y;
            acc4.z += a * r[d].z; acc4.w += a * r[d].w;
        }
        *(float4*)(&sX[mrow][lane * 4]) = acc4;
    }
    __syncthreads();

    // ---- Phase B: h = cond_relu(mlp_n(sX)) ----
    // layer 1: (32x256)@(256x128), lrelu
    {
        const int tj = tid & 31, tr = tid >> 5;
        float acc[2][4];
        #pragma unroll
        for (int a = 0; a < 2; ++a)
            #pragma unroll
            for (int b = 0; b < 4; ++b) acc[a][b] = 0.f;

        for (int k = 0; k < NH; k += 4) {
            float4 w0 = *(const float4*)(W1 + (size_t)(k + 0) * 128 + tj * 4);
            float4 w1 = *(const float4*)(W1 + (size_t)(k + 1) * 128 + tj * 4);
            float4 w2 = *(const float4*)(W1 + (size_t)(k + 2) * 128 + tj * 4);
            float4 w3 = *(const float4*)(W1 + (size_t)(k + 3) * 128 + tj * 4);
            #pragma unroll
            for (int rr = 0; rr < 2; ++rr) {
                float4 xv = *(const float4*)(&sX[tr * 2 + rr][k]);
                acc[rr][0] += xv.x * w0.x + xv.y * w1.x + xv.z * w2.x + xv.w * w3.x;
                acc[rr][1] += xv.x * w0.y + xv.y * w1.y + xv.z * w2.y + xv.w * w3.y;
                acc[rr][2] += xv.x * w0.z + xv.y * w1.z + xv.z * w2.z + xv.w * w3.z;
                acc[rr][3] += xv.x * w0.w + xv.y * w1.w + xv.z * w2.w + xv.w * w3.w;
            }
        }
        float4 bv = *(const float4*)(b1 + tj * 4);
        #pragma unroll
        for (int rr = 0; rr < 2; ++rr) {
            float4 o;
            o.x = lrelu(acc[rr][0] + bv.x); o.y = lrelu(acc[rr][1] + bv.y);
            o.z = lrelu(acc[rr][2] + bv.z); o.w = lrelu(acc[rr][3] + bv.w);
            *(float4*)(&sH[tr * 2 + rr][tj * 4]) = o;
        }
    }
    __syncthreads();

    // layer 2: (32x128)@(128x256), cond-relu, store to h_out
    {
        const int tj = tid & 63, tr = tid >> 6;
        float acc[4][4];
        #pragma unroll
        for (int a = 0; a < 4; ++a)
            #pragma unroll
            for (int b = 0; b < 4; ++b) acc[a][b] = 0.f;

        for (int k = 0; k < 128; k += 4) {
            float4 w0 = *(const float4*)(W2 + (size_t)(k + 0) * 256 + tj * 4);
            float4 w1 = *(const float4*)(W2 + (size_t)(k + 1) * 256 + tj * 4);
            float4 w2 = *(const float4*)(W2 + (size_t)(k + 2) * 256 + tj * 4);
            float4 w3 = *(const float4*)(W2 + (size_t)(k + 3) * 256 + tj * 4);
            #pragma unroll
            for (int rr = 0; rr < 4; ++rr) {
                float4 xv = *(const float4*)(&sH[tr * 4 + rr][k]);
                acc[rr][0] += xv.x * w0.x + xv.y * w1.x + xv.z * w2.x + xv.w * w3.x;
                acc[rr][1] += xv.x * w0.y + xv.y * w1.y + xv.z * w2.y + xv.w * w3.y;
                acc[rr][2] += xv.x * w0.z + xv.y * w1.z + xv.z * w2.z + xv.w * w3.z;
                acc[rr][3] += xv.x * w0.w + xv.y * w1.w + xv.z * w2.w + xv.w * w3.w;
            }
        }
        float4 bv = *(const float4*)(b2 + tj * 4);
        #pragma unroll
        for (int rr = 0; rr < 4; ++rr) {
            int gm = level * NM + row0 + tr * 4 + rr;
            bool po = (is_po[gm] == 1);
            float4 o;
            o.x = acc[rr][0] + bv.x; o.y = acc[rr][1] + bv.y;
            o.z = acc[rr][2] + bv.z; o.w = acc[rr][3] + bv.w;
            if (!po) {
                o.x = fmaxf(o.x, 0.f); o.y = fmaxf(o.y, 0.f);
                o.z = fmaxf(o.z, 0.f); o.w = fmaxf(o.w, 0.f);
            }
            *(float4*)(h_out + (size_t)gm * NH + tj * 4) = o;
        }
    }
}

// ---------- Final readout: 256 thr / 16 rows; Wo2 dot fused into o1 pass ----------
__global__ __launch_bounds__(256) void final_kernel(
    const float* __restrict__ h_gnn, const float* __restrict__ po_feat,
    const float* __restrict__ Wg1, const float* __restrict__ bg1,
    const float* __restrict__ Wg2, const float* __restrict__ bg2,
    const float* __restrict__ Wo1, const float* __restrict__ bo1,
    const float* __restrict__ Wo2, const float* __restrict__ bo2,
    float* __restrict__ out)
{
    const int tid = threadIdx.x;
    const int row0 = blockIdx.x * 16;
    __shared__ __align__(16) float sx[16][512];
    __shared__ __align__(16) float sg[16][128];

    for (int x = tid; x < 16 * 64; x += 256) {
        int r = x >> 6, c = x & 63;
        *(float4*)(&sx[r][c * 4]) = *(const float4*)(h_gnn + (size_t)(row0 + r) * NH + c * 4);
    }
    for (int x = tid; x < 16 * 128; x += 256) {
        int r = x >> 7, j = x & 127;
        sg[r][j] = lrelu(po_feat[row0 + r] * Wg1[j] + bg1[j]);
    }
    __syncthreads();

    // h_global = sg @ Wg2 + bg2 -> sx[:, 256:]
    {
        const int tj = tid & 63, tr = tid >> 6;
        float acc[4][4];
        #pragma unroll
        for (int a = 0; a < 4; ++a)
            #pragma unroll
            for (int b = 0; b < 4; ++b) acc[a][b] = 0.f;

        for (int k = 0; k < 128; k += 4) {
            float4 w0 = *(const float4*)(Wg2 + (size_t)(k + 0) * 256 + tj * 4);
            float4 w1 = *(const float4*)(Wg2 + (size_t)(k + 1) * 256 + tj * 4);
            float4 w2 = *(const float4*)(Wg2 + (size_t)(k + 2) * 256 + tj * 4);
            float4 w3 = *(const float4*)(Wg2 + (size_t)(k + 3) * 256 + tj * 4);
            #pragma unroll
            for (int rr = 0; rr < 4; ++rr) {
                float4 xv = *(const float4*)(&sg[tr * 4 + rr][k]);
                acc[rr][0] += xv.x * w0.x + xv.y * w1.x + xv.z * w2.x + xv.w * w3.x;
                acc[rr][1] += xv.x * w0.y + xv.y * w1.y + xv.z * w2.y + xv.w * w3.y;
                acc[rr][2] += xv.x * w0.z + xv.y * w1.z + xv.z * w2.z + xv.w * w3.z;
                acc[rr][3] += xv.x * w0.w + xv.y * w1.w + xv.z * w2.w + xv.w * w3.w;
            }
        }
        float4 bv = *(const float4*)(bg2 + tj * 4);
        #pragma unroll
        for (int rr = 0; rr < 4; ++rr) {
            float4 o;
            o.x = acc[rr][0] + bv.x; o.y = acc[rr][1] + bv.y;
            o.z = acc[rr][2] + bv.z; o.w = acc[rr][3] + bv.w;
            *(float4*)(&sx[tr * 4 + rr][256 + tj * 4]) = o;
        }
    }
    __syncthreads();

    // o1 = lrelu(sx @ Wo1 + bo1) fused with out = o1 @ Wo2 + bo2
    {
        const int tj = tid & 63, tr = tid >> 6;   // wave tr owns rows tr*4..tr*4+3
        float acc[4][4];
        #pragma unroll
        for (int a = 0; a < 4; ++a)
            #pragma unroll
            for (int b = 0; b < 4; ++b) acc[a][b] = 0.f;

        for (int k = 0; k < 512; k += 4) {
            float4 w0 = *(const float4*)(Wo1 + (size_t)(k + 0) * 256 + tj * 4);
            float4 w1 = *(const float4*)(Wo1 + (size_t)(k + 1) * 256 + tj * 4);
            float4 w2 = *(const float4*)(Wo1 + (size_t)(k + 2) * 256 + tj * 4);
            float4 w3 = *(const float4*)(Wo1 + (size_t)(k + 3) * 256 + tj * 4);
            #pragma unroll
            for (int rr = 0; rr < 4; ++rr) {
                float4 xv = *(const float4*)(&sx[tr * 4 + rr][k]);
                acc[rr][0] += xv.x * w0.x + xv.y * w1.x + xv.z * w2.x + xv.w * w3.x;
                acc[rr][1] += xv.x * w0.y + xv.y * w1.y + xv.z * w2.y + xv.w * w3.y;
                acc[rr][2] += xv.x * w0.z + xv.y * w1.z + xv.z * w2.z + xv.w * w3.z;
                acc[rr][3] += xv.x * w0.w + xv.y * w1.w + xv.z * w2.w + xv.w * w3.w;
            }
        }
        float4 bv = *(const float4*)(bo1 + tj * 4);
        float4 wv = *(const float4*)(Wo2 + tj * 4);
        #pragma unroll
        for (int rr = 0; rr < 4; ++rr) {
            float c = lrelu(acc[rr][0] + bv.x) * wv.x
                    + lrelu(acc[rr][1] + bv.y) * wv.y
                    + lrelu(acc[rr][2] + bv.z) * wv.z
                    + lrelu(acc[rr][3] + bv.w) * wv.w;
            #pragma unroll
            for (int off = 1; off < 64; off <<= 1) c += __shfl_xor(c, off);
            if (tj == 0) out[row0 + tr * 4 + rr] = c + bo2[0];
        }
    }
}

extern "C" void kernel_launch(void* const* d_in, const int* in_sizes, int n_in,
                              void* d_out, int out_size, void* d_ws, size_t ws_size,
                              hipStream_t stream) {
    const float* W_pi1 = (const float*)d_in[0];
    const float* b_pi1 = (const float*)d_in[1];
    const float* W_pi2 = (const float*)d_in[2];
    const float* b_pi2 = (const float*)d_in[3];
    const float* W_t1  = (const float*)d_in[4];
    const float* b_t1  = (const float*)d_in[5];
    const float* W_t2  = (const float*)d_in[6];
    const float* b_t2  = (const float*)d_in[7];
    const float* W_p1  = (const float*)d_in[8];
    const float* b_p1  = (const float*)d_in[9];
    const float* W_p2  = (const float*)d_in[10];
    const float* b_p2  = (const float*)d_in[11];
    const float* W_n1  = (const float*)d_in[12];
    const float* b_n1  = (const float*)d_in[13];
    const float* W_n2  = (const float*)d_in[14];
    const float* b_n2  = (const float*)d_in[15];
    const float* W_g1  = (const float*)d_in[16];
    const float* b_g1  = (const float*)d_in[17];
    const float* W_g2  = (const float*)d_in[18];
    const float* b_g2  = (const float*)d_in[19];
    const float* W_o1  = (const float*)d_in[20];
    const float* b_o1  = (const float*)d_in[21];
    const float* W_o2  = (const float*)d_in[22];
    const float* b_o2  = (const float*)d_in[23];
    const float* av    = (const float*)d_in[24];
    const float* feat  = (const float*)d_in[25];
    const float* delay = (const float*)d_in[26];
    const float* bit_pos = (const float*)d_in[27];
    const float* po_feat = (const float*)d_in[28];
    const int*   is_po   = (const int*)d_in[29];
    const int*   nbr_idx = (const int*)d_in[30];

    float* h_all = (float*)d_ws;                       // NN*256 floats
    float* cst   = h_all + (size_t)NN * NH;            // 128 floats
    float* out   = (float*)d_out;

    precomp_kernel<<<1, 64, 0, stream>>>(W_t2, b_t2, W_p2, b_p2, av, cst);

    level0_kernel<<<NM / 32, 512, 0, stream>>>(delay, W_pi1, b_pi1, W_pi2, b_pi2, h_all);

    for (int level = 1; level < NL; ++level) {
        level_kernel<<<NM / 32, 512, 0, stream>>>(h_all, feat, bit_pos, nbr_idx,
                                                  W_t1, b_t1, W_p1, b_p1,
                                                  av, cst,
                                                  W_n1, b_n1, W_n2, b_n2,
                                                  is_po, h_all, level);
    }

    final_kernel<<<NM / 16, 256, 0, stream>>>(h_all + (size_t)(NN - NM) * NH, po_feat,
                                              W_g1, b_g1, W_g2, b_g2,
                                              W_o1, b_o1, W_o2, b_o2, out);
}

// Round 4
// 419.262 us; speedup vs baseline: 1.9594x; 1.9594x over previous
//
#include <hip/hip_runtime.h>

#define NL 8
#define NM 8192
#define ND 16
#define NH 256
#define NF 64
#define NN (NL * NM)

__device__ __forceinline__ float lrelu(float x) { return fmaxf(x, 0.1f * x); }

// ---------- precompute attention constants: cst[32..63] = W_p2 @ av_p ----------
__global__ void precomp_kernel(const float* __restrict__ W_t2, const float* __restrict__ b_t2,
                               const float* __restrict__ W_p2, const float* __restrict__ b_p2,
                               const float* __restrict__ av, float* __restrict__ cst)
{
    int t = threadIdx.x;
    if (t < 32) {
        float w = 0.f;
        for (int q = 0; q < 32; ++q) w += W_t2[t * 32 + q] * av[q];
        cst[t] = w;
    } else {
        int j = t - 32;
        float w = 0.f;
        for (int k = 0; k < 32; ++k) w += W_p2[j * 32 + k] * av[32 + k];
        cst[32 + j] = w;
    }
}

// ---------- Level 0: h = mlp_pi(delay) + g epilogue ----------
__global__ __launch_bounds__(512) void level0_kernel(
    const float* __restrict__ delay,
    const float* __restrict__ W1, const float* __restrict__ b1,
    const float* __restrict__ W2, const float* __restrict__ b2,
    const float* __restrict__ av,
    float* __restrict__ h_all, float* __restrict__ g_all)
{
    const int tid = threadIdx.x;
    const int row0 = blockIdx.x * 32;
    __shared__ __align__(16) float sH[32][128];

    for (int x = tid; x < 32 * 128; x += 512) {
        int r = x >> 7, j = x & 127;
        sH[r][j] = lrelu(delay[row0 + r] * W1[j] + b1[j]);
    }
    __syncthreads();

    const int tj = tid & 63, tr = tid >> 6;
    const float4 av4 = *(const float4*)(av + 64 + tj * 4);
    float acc[4][4];
    #pragma unroll
    for (int a = 0; a < 4; ++a)
        #pragma unroll
        for (int b = 0; b < 4; ++b) acc[a][b] = 0.f;

    for (int k = 0; k < 128; k += 4) {
        float4 w0 = *(const float4*)(W2 + (size_t)(k + 0) * 256 + tj * 4);
        float4 w1 = *(const float4*)(W2 + (size_t)(k + 1) * 256 + tj * 4);
        float4 w2 = *(const float4*)(W2 + (size_t)(k + 2) * 256 + tj * 4);
        float4 w3 = *(const float4*)(W2 + (size_t)(k + 3) * 256 + tj * 4);
        #pragma unroll
        for (int rr = 0; rr < 4; ++rr) {
            float4 xv = *(const float4*)(&sH[tr * 4 + rr][k]);
            acc[rr][0] += xv.x * w0.x + xv.y * w1.x + xv.z * w2.x + xv.w * w3.x;
            acc[rr][1] += xv.x * w0.y + xv.y * w1.y + xv.z * w2.y + xv.w * w3.y;
            acc[rr][2] += xv.x * w0.z + xv.y * w1.z + xv.z * w2.z + xv.w * w3.z;
            acc[rr][3] += xv.x * w0.w + xv.y * w1.w + xv.z * w2.w + xv.w * w3.w;
        }
    }
    float4 bv = *(const float4*)(b2 + tj * 4);
    #pragma unroll
    for (int rr = 0; rr < 4; ++rr) {
        const int row = row0 + tr * 4 + rr;
        float4 o;
        o.x = acc[rr][0] + bv.x; o.y = acc[rr][1] + bv.y;
        o.z = acc[rr][2] + bv.z; o.w = acc[rr][3] + bv.w;
        *(float4*)(h_all + (size_t)row * NH + tj * 4) = o;
        float gp = o.x * av4.x + o.y * av4.y + o.z * av4.z + o.w * av4.w;
        #pragma unroll
        for (int off = 1; off < 64; off <<= 1) gp += __shfl_xor(gp, off);
        if (tj == 0) g_all[row] = gp;
    }
}

// ---------- Attention per level: 1 wave per m; g-gather alpha + single streamed pass ----------
__global__ __launch_bounds__(256) void attn_kernel(
    const float* __restrict__ h_all, const float* __restrict__ g_all,
    const float* __restrict__ bit_pos, const int* __restrict__ nbr_idx,
    const float* __restrict__ W_p1, const float* __restrict__ b_p1,
    const float* __restrict__ cst,
    float* __restrict__ neigh, int level)
{
    const int w = threadIdx.x >> 6, lane = threadIdx.x & 63;
    const int m = blockIdx.x * 4 + w;
    const int d = lane & 15, jj = lane >> 4;
    const size_t ebase = ((size_t)(level - 1) * NM + m) * ND;

    const int   idx = nbr_idx[ebase + d];
    const float bp  = bit_pos[ebase + d];

    // collapsed mlp_p: 4 jj-groups each cover 8 of the 32 hidden units
    float ep = 0.f;
    #pragma unroll
    for (int t = 0; t < 8; ++t) {
        int j = jj * 8 + t;
        ep += cst[32 + j] * lrelu(bp * W_p1[j] + b_p1[j]);
    }
    ep += __shfl_xor(ep, 16);
    ep += __shfl_xor(ep, 32);

    // e = e_h + e_p  (e_t is constant over d -> cancels in softmax)
    float e = g_all[idx] + ep;
    float mx = e;
    #pragma unroll
    for (int off = 1; off < 16; off <<= 1) mx = fmaxf(mx, __shfl_xor(mx, off));
    float wexp = __expf(e - mx);
    float s = wexp;
    #pragma unroll
    for (int off = 1; off < 16; off <<= 1) s += __shfl_xor(s, off);
    const float alpha = wexp / s;

    // single streamed weighted sum: 16 independent 1KB row loads
    float4 acc = make_float4(0.f, 0.f, 0.f, 0.f);
    #pragma unroll
    for (int d2 = 0; d2 < 16; ++d2) {
        float a = __shfl(alpha, d2);
        int   r = __shfl(idx, d2);
        float4 v = *(const float4*)(h_all + (size_t)r * NH + lane * 4);
        acc.x += a * v.x; acc.y += a * v.y; acc.z += a * v.z; acc.w += a * v.w;
    }
    *(float4*)(neigh + (size_t)m * NH + lane * 4) = acc;
}

// ---------- Neighborhood MLP: 256 thr / 16 rows / 512 blocks + g epilogue ----------
__global__ __launch_bounds__(256) void mlp_n_kernel(
    const float* __restrict__ neigh,
    const float* __restrict__ W1, const float* __restrict__ b1,
    const float* __restrict__ W2, const float* __restrict__ b2,
    const int* __restrict__ is_po, const float* __restrict__ av,
    float* __restrict__ h_all, float* __restrict__ g_all, int level)
{
    const int tid = threadIdx.x;
    const int row0 = blockIdx.x * 16;
    __shared__ __align__(16) float sX[16][NH];
    __shared__ __align__(16) float sH[16][128];

    for (int x = tid; x < 16 * 64; x += 256) {
        int r = x >> 6, c = x & 63;
        *(float4*)(&sX[r][c * 4]) = *(const float4*)(neigh + (size_t)(row0 + r) * NH + c * 4);
    }
    __syncthreads();

    // layer 1: (16x256)@(256x128), lrelu
    {
        const int tj = tid & 31, tr = tid >> 5;   // 32 col-thr x 4 cols; 8 row-groups x 2 rows
        float acc[2][4];
        #pragma unroll
        for (int a = 0; a < 2; ++a)
            #pragma unroll
            for (int b = 0; b < 4; ++b) acc[a][b] = 0.f;

        for (int k = 0; k < NH; k += 4) {
            float4 w0 = *(const float4*)(W1 + (size_t)(k + 0) * 128 + tj * 4);
            float4 w1 = *(const float4*)(W1 + (size_t)(k + 1) * 128 + tj * 4);
            float4 w2 = *(const float4*)(W1 + (size_t)(k + 2) * 128 + tj * 4);
            float4 w3 = *(const float4*)(W1 + (size_t)(k + 3) * 128 + tj * 4);
            #pragma unroll
            for (int rr = 0; rr < 2; ++rr) {
                float4 xv = *(const float4*)(&sX[tr * 2 + rr][k]);
                acc[rr][0] += xv.x * w0.x + xv.y * w1.x + xv.z * w2.x + xv.w * w3.x;
                acc[rr][1] += xv.x * w0.y + xv.y * w1.y + xv.z * w2.y + xv.w * w3.y;
                acc[rr][2] += xv.x * w0.z + xv.y * w1.z + xv.z * w2.z + xv.w * w3.z;
                acc[rr][3] += xv.x * w0.w + xv.y * w1.w + xv.z * w2.w + xv.w * w3.w;
            }
        }
        float4 bv = *(const float4*)(b1 + tj * 4);
        #pragma unroll
        for (int rr = 0; rr < 2; ++rr) {
            float4 o;
            o.x = lrelu(acc[rr][0] + bv.x); o.y = lrelu(acc[rr][1] + bv.y);
            o.z = lrelu(acc[rr][2] + bv.z); o.w = lrelu(acc[rr][3] + bv.w);
            *(float4*)(&sH[tr * 2 + rr][tj * 4]) = o;
        }
    }
    __syncthreads();

    // layer 2: (16x128)@(128x256), cond-relu, store + g epilogue
    {
        const int tj = tid & 63, tr = tid >> 6;   // 64 col-thr x 4 cols; 4 row-groups x 4 rows
        const float4 av4 = *(const float4*)(av + 64 + tj * 4);
        float acc[4][4];
        #pragma unroll
        for (int a = 0; a < 4; ++a)
            #pragma unroll
            for (int b = 0; b < 4; ++b) acc[a][b] = 0.f;

        for (int k = 0; k < 128; k += 4) {
            float4 w0 = *(const float4*)(W2 + (size_t)(k + 0) * 256 + tj * 4);
            float4 w1 = *(const float4*)(W2 + (size_t)(k + 1) * 256 + tj * 4);
            float4 w2 = *(const float4*)(W2 + (size_t)(k + 2) * 256 + tj * 4);
            float4 w3 = *(const float4*)(W2 + (size_t)(k + 3) * 256 + tj * 4);
            #pragma unroll
            for (int rr = 0; rr < 4; ++rr) {
                float4 xv = *(const float4*)(&sH[tr * 4 + rr][k]);
                acc[rr][0] += xv.x * w0.x + xv.y * w1.x + xv.z * w2.x + xv.w * w3.x;
                acc[rr][1] += xv.x * w0.y + xv.y * w1.y + xv.z * w2.y + xv.w * w3.y;
                acc[rr][2] += xv.x * w0.z + xv.y * w1.z + xv.z * w2.z + xv.w * w3.z;
                acc[rr][3] += xv.x * w0.w + xv.y * w1.w + xv.z * w2.w + xv.w * w3.w;
            }
        }
        float4 bv = *(const float4*)(b2 + tj * 4);
        #pragma unroll
        for (int rr = 0; rr < 4; ++rr) {
            const int gm = level * NM + row0 + tr * 4 + rr;
            bool po = (is_po[gm] == 1);
            float4 o;
            o.x = acc[rr][0] + bv.x; o.y = acc[rr][1] + bv.y;
            o.z = acc[rr][2] + bv.z; o.w = acc[rr][3] + bv.w;
            if (!po) {
                o.x = fmaxf(o.x, 0.f); o.y = fmaxf(o.y, 0.f);
                o.z = fmaxf(o.z, 0.f); o.w = fmaxf(o.w, 0.f);
            }
            *(float4*)(h_all + (size_t)gm * NH + tj * 4) = o;
            float gp = o.x * av4.x + o.y * av4.y + o.z * av4.z + o.w * av4.w;
            #pragma unroll
            for (int off = 1; off < 64; off <<= 1) gp += __shfl_xor(gp, off);
            if (tj == 0) g_all[gm] = gp;
        }
    }
}

// ---------- Final readout: 256 thr / 16 rows; Wo2 dot fused into o1 pass ----------
__global__ __launch_bounds__(256) void final_kernel(
    const float* __restrict__ h_gnn, const float* __restrict__ po_feat,
    const float* __restrict__ Wg1, const float* __restrict__ bg1,
    const float* __restrict__ Wg2, const float* __restrict__ bg2,
    const float* __restrict__ Wo1, const float* __restrict__ bo1,
    const float* __restrict__ Wo2, const float* __restrict__ bo2,
    float* __restrict__ out)
{
    const int tid = threadIdx.x;
    const int row0 = blockIdx.x * 16;
    __shared__ __align__(16) float sx[16][512];
    __shared__ __align__(16) float sg[16][128];

    for (int x = tid; x < 16 * 64; x += 256) {
        int r = x >> 6, c = x & 63;
        *(float4*)(&sx[r][c * 4]) = *(const float4*)(h_gnn + (size_t)(row0 + r) * NH + c * 4);
    }
    for (int x = tid; x < 16 * 128; x += 256) {
        int r = x >> 7, j = x & 127;
        sg[r][j] = lrelu(po_feat[row0 + r] * Wg1[j] + bg1[j]);
    }
    __syncthreads();

    // h_global = sg @ Wg2 + bg2 -> sx[:, 256:]
    {
        const int tj = tid & 63, tr = tid >> 6;
        float acc[4][4];
        #pragma unroll
        for (int a = 0; a < 4; ++a)
            #pragma unroll
            for (int b = 0; b < 4; ++b) acc[a][b] = 0.f;

        for (int k = 0; k < 128; k += 4) {
            float4 w0 = *(const float4*)(Wg2 + (size_t)(k + 0) * 256 + tj * 4);
            float4 w1 = *(const float4*)(Wg2 + (size_t)(k + 1) * 256 + tj * 4);
            float4 w2 = *(const float4*)(Wg2 + (size_t)(k + 2) * 256 + tj * 4);
            float4 w3 = *(const float4*)(Wg2 + (size_t)(k + 3) * 256 + tj * 4);
            #pragma unroll
            for (int rr = 0; rr < 4; ++rr) {
                float4 xv = *(const float4*)(&sg[tr * 4 + rr][k]);
                acc[rr][0] += xv.x * w0.x + xv.y * w1.x + xv.z * w2.x + xv.w * w3.x;
                acc[rr][1] += xv.x * w0.y + xv.y * w1.y + xv.z * w2.y + xv.w * w3.y;
                acc[rr][2] += xv.x * w0.z + xv.y * w1.z + xv.z * w2.z + xv.w * w3.z;
                acc[rr][3] += xv.x * w0.w + xv.y * w1.w + xv.z * w2.w + xv.w * w3.w;
            }
        }
        float4 bv = *(const float4*)(bg2 + tj * 4);
        #pragma unroll
        for (int rr = 0; rr < 4; ++rr) {
            float4 o;
            o.x = acc[rr][0] + bv.x; o.y = acc[rr][1] + bv.y;
            o.z = acc[rr][2] + bv.z; o.w = acc[rr][3] + bv.w;
            *(float4*)(&sx[tr * 4 + rr][256 + tj * 4]) = o;
        }
    }
    __syncthreads();

    // o1 = lrelu(sx @ Wo1 + bo1) fused with out = o1 @ Wo2 + bo2
    {
        const int tj = tid & 63, tr = tid >> 6;
        float acc[4][4];
        #pragma unroll
        for (int a = 0; a < 4; ++a)
            #pragma unroll
            for (int b = 0; b < 4; ++b) acc[a][b] = 0.f;

        for (int k = 0; k < 512; k += 4) {
            float4 w0 = *(const float4*)(Wo1 + (size_t)(k + 0) * 256 + tj * 4);
            float4 w1 = *(const float4*)(Wo1 + (size_t)(k + 1) * 256 + tj * 4);
            float4 w2 = *(const float4*)(Wo1 + (size_t)(k + 2) * 256 + tj * 4);
            float4 w3 = *(const float4*)(Wo1 + (size_t)(k + 3) * 256 + tj * 4);
            #pragma unroll
            for (int rr = 0; rr < 4; ++rr) {
                float4 xv = *(const float4*)(&sx[tr * 4 + rr][k]);
                acc[rr][0] += xv.x * w0.x + xv.y * w1.x + xv.z * w2.x + xv.w * w3.x;
                acc[rr][1] += xv.x * w0.y + xv.y * w1.y + xv.z * w2.y + xv.w * w3.y;
                acc[rr][2] += xv.x * w0.z + xv.y * w1.z + xv.z * w2.z + xv.w * w3.z;
                acc[rr][3] += xv.x * w0.w + xv.y * w1.w + xv.z * w2.w + xv.w * w3.w;
            }
        }
        float4 bv = *(const float4*)(bo1 + tj * 4);
        float4 wv = *(const float4*)(Wo2 + tj * 4);
        #pragma unroll
        for (int rr = 0; rr < 4; ++rr) {
            float c = lrelu(acc[rr][0] + bv.x) * wv.x
                    + lrelu(acc[rr][1] + bv.y) * wv.y
                    + lrelu(acc[rr][2] + bv.z) * wv.z
                    + lrelu(acc[rr][3] + bv.w) * wv.w;
            #pragma unroll
            for (int off = 1; off < 64; off <<= 1) c += __shfl_xor(c, off);
            if (tj == 0) out[row0 + tr * 4 + rr] = c + bo2[0];
        }
    }
}

extern "C" void kernel_launch(void* const* d_in, const int* in_sizes, int n_in,
                              void* d_out, int out_size, void* d_ws, size_t ws_size,
                              hipStream_t stream) {
    const float* W_pi1 = (const float*)d_in[0];
    const float* b_pi1 = (const float*)d_in[1];
    const float* W_pi2 = (const float*)d_in[2];
    const float* b_pi2 = (const float*)d_in[3];
    const float* W_t1  = (const float*)d_in[4];
    const float* b_t1  = (const float*)d_in[5];
    const float* W_t2  = (const float*)d_in[6];
    const float* b_t2  = (const float*)d_in[7];
    const float* W_p1  = (const float*)d_in[8];
    const float* b_p1  = (const float*)d_in[9];
    const float* W_p2  = (const float*)d_in[10];
    const float* b_p2  = (const float*)d_in[11];
    const float* W_n1  = (const float*)d_in[12];
    const float* b_n1  = (const float*)d_in[13];
    const float* W_n2  = (const float*)d_in[14];
    const float* b_n2  = (const float*)d_in[15];
    const float* W_g1  = (const float*)d_in[16];
    const float* b_g1  = (const float*)d_in[17];
    const float* W_g2  = (const float*)d_in[18];
    const float* b_g2  = (const float*)d_in[19];
    const float* W_o1  = (const float*)d_in[20];
    const float* b_o1  = (const float*)d_in[21];
    const float* W_o2  = (const float*)d_in[22];
    const float* b_o2  = (const float*)d_in[23];
    const float* av    = (const float*)d_in[24];
    const float* feat  = (const float*)d_in[25];
    const float* delay = (const float*)d_in[26];
    const float* bit_pos = (const float*)d_in[27];
    const float* po_feat = (const float*)d_in[28];
    const int*   is_po   = (const int*)d_in[29];
    const int*   nbr_idx = (const int*)d_in[30];
    (void)feat; (void)W_t1; (void)b_t1;   // e_t cancels in softmax

    float* h_all = (float*)d_ws;                       // NN*NH floats
    float* g_all = h_all + (size_t)NN * NH;            // NN floats
    float* neigh = g_all + NN;                         // NM*NH floats
    float* cst   = neigh + (size_t)NM * NH;            // 64 floats
    float* out   = (float*)d_out;

    precomp_kernel<<<1, 64, 0, stream>>>(W_t2, b_t2, W_p2, b_p2, av, cst);

    level0_kernel<<<NM / 32, 512, 0, stream>>>(delay, W_pi1, b_pi1, W_pi2, b_pi2,
                                               av, h_all, g_all);

    for (int level = 1; level < NL; ++level) {
        attn_kernel<<<NM / 4, 256, 0, stream>>>(h_all, g_all, bit_pos, nbr_idx,
                                                W_p1, b_p1, cst, neigh, level);
        mlp_n_kernel<<<NM / 16, 256, 0, stream>>>(neigh, W_n1, b_n1, W_n2, b_n2,
                                                  is_po, av, h_all, g_all, level);
    }

    final_kernel<<<NM / 16, 256, 0, stream>>>(h_all + (size_t)(NN - NM) * NH, po_feat,
                                              W_g1, b_g1, W_g2, b_g2,
                                              W_o1, b_o1, W_o2, b_o2, out);
}